// Round 16
// baseline (229.747 us; speedup 1.0000x reference)
//
#include <hip/hip_runtime.h>
#include <stdint.h>

#define S_LEN 2048
#define NTOK  4096      // B*S
#define DMODEL 2048
#define NHQ 32
#define NHKV 8

typedef _Float16 half8 __attribute__((ext_vector_type(8)));
typedef _Float16 half4v __attribute__((ext_vector_type(4)));
typedef __fp16 fp16x2 __attribute__((ext_vector_type(2)));
typedef float f32x4 __attribute__((ext_vector_type(4)));
typedef float f32x16 __attribute__((ext_vector_type(16)));

#define MFMA16(a,b,c) __builtin_amdgcn_mfma_f32_16x16x32_f16(a,b,c,0,0,0)
#define MFMA32(a,b,c) __builtin_amdgcn_mfma_f32_32x32x16_f16(a,b,c,0,0,0)

__device__ __forceinline__ void gload16(const void* g, void* l) {
  __builtin_amdgcn_global_load_lds(
      (const __attribute__((address_space(1))) void*)g,
      (__attribute__((address_space(3))) void*)l, 16, 0, 0);
}

__device__ __forceinline__ float fexp2(float x) {
#if __has_builtin(__builtin_amdgcn_exp2f)
  return __builtin_amdgcn_exp2f(x);
#else
  float r; asm("v_exp_f32 %0, %1" : "=v"(r) : "v"(x)); return r;
#endif
}

__device__ __forceinline__ int cvt_pk(float a, float b) {
  fp16x2 r = __builtin_amdgcn_cvt_pkrtz(a, b);
  return __builtin_bit_cast(int, r);
}

// ---------------- prep kernel (weight transposes + x cast, one launch) ----------------
// blockIdx.y: 0-63 Wq | 64-79 Wk | 80-95 Wv | 96-159 Wo | 160-287 cast_x
__global__ void prep_all(const float* __restrict__ x,
                         const float* __restrict__ Wq, const float* __restrict__ Wk,
                         const float* __restrict__ Wv, const float* __restrict__ Wo,
                         _Float16* __restrict__ xs,
                         _Float16* __restrict__ Wall, _Float16* __restrict__ Wot) {
  __shared__ float tile[32][33];
  const int K = 2048;
  int y = blockIdx.y;
  if (y >= 160) {   // cast_x: fp32 [NTOK][DMODEL] -> fp16
    size_t bi = (size_t)(y - 160) * 64 + blockIdx.x;
    size_t i = (bi * 256 + threadIdx.x) * 4;
    float4 v = *(const float4*)(x + i);
    half4v o = {(_Float16)v.x, (_Float16)v.y, (_Float16)v.z, (_Float16)v.w};
    *(half4v*)(xs + i) = o;
    return;
  }
  const float* W;
  _Float16* Wt;
  int N;
  if (y < 64)      { W = Wq; Wt = Wall;                          N = 2048; }
  else if (y < 80) { W = Wk; Wt = Wall + (size_t)2048 * 2048;    N = 512;  y -= 64; }
  else if (y < 96) { W = Wv; Wt = Wall + (size_t)2560 * 2048;    N = 512;  y -= 80; }
  else             { W = Wo; Wt = Wot;                           N = 2048; y -= 96; }
  int kt = blockIdx.x * 32, nt = y * 32;
  int r = threadIdx.x >> 5, c = threadIdx.x & 31;
#pragma unroll
  for (int i = 0; i < 4; i++)
    tile[r + i * 8][c] = W[(size_t)(kt + r + i * 8) * N + nt + c];
  __syncthreads();
#pragma unroll
  for (int i = 0; i < 4; i++) {
    int rr = r + i * 8;
    Wt[(size_t)(nt + rr) * K + kt + c] = (_Float16)tile[c][rr];
  }
}

// ---------------- GEMM: C = A(MxK) * Bt(NxK)^T, fp16 in / fp32 acc ----------------
// 128x128 tile, BK=32, 512 threads (8 waves, 4Mx2N, wave tile 32x64),
// double-buffered prefetch (T3-min) + XCD swizzle (T1). (r13 known-good.)
// MODE 0: fused QKV epilogue (N=3072); MODE 2: O epilogue (N=2048).
template<int MODE>
__global__ __launch_bounds__(512, 6) void gemm_nt(
    const _Float16* __restrict__ A, const _Float16* __restrict__ Bt, int K,
    const float* __restrict__ bias1, const float* __restrict__ bias2,
    const float* __restrict__ bias3,
    _Float16* __restrict__ outQ, _Float16* __restrict__ outK,
    _Float16* __restrict__ outV, float* __restrict__ outF)
{
  __shared__ __align__(16) _Float16 As[2][128 * 32];
  __shared__ __align__(16) _Float16 Bs[2][128 * 32];
  const int tid = threadIdx.x;
  const int w = tid >> 6, l = tid & 63;
  const int wr = w >> 1, wc = w & 1;   // 4 M-quadrants x 2 N-halves

  // T1: bijective XCD swizzle (nwg multiple of 8; gridDim.x == 32)
  const int lin = blockIdx.x + blockIdx.y * 32;
  const int nwg = 32 * gridDim.y;
  const int swz = (lin & 7) * (nwg >> 3) + (lin >> 3);
  const int row0 = (swz & 31) * 128, col0 = (swz >> 5) * 128;

  f32x4 acc[2][4] = {};

  const int lr = l >> 2;                      // staging row-in-16
  const int scol = 8 * ((l & 3) ^ (lr & 3));  // pre-swizzled source col
  const _Float16* Abase = A + (size_t)row0 * K;
  const _Float16* Bbase = Bt + (size_t)col0 * K;

  const int fr = l & 15;
  const int rswz = 8 * ((l >> 4) ^ (l & 3));  // kk ^ ((row&3)*8)

  // wave w stages rows w*16..w*16+15 of both tiles: 1 A + 1 B gload per thread
#define GSTAGE(buf, kt)                                                       \
  {                                                                           \
    int r = w * 16 + lr;                                                      \
    gload16(Abase + (size_t)r * K + (kt) * 32 + scol, &As[buf][(w * 16) * 32]); \
    gload16(Bbase + (size_t)r * K + (kt) * 32 + scol, &Bs[buf][(w * 16) * 32]); \
  }

  const int NK = K >> 5;
  GSTAGE(0, 0);
  __syncthreads();

  for (int kt = 0; kt < NK; kt++) {
    const int cur = kt & 1;
    if (kt + 1 < NK) GSTAGE(cur ^ 1, kt + 1);

    half8 af[2], bf[4];
#pragma unroll
    for (int m = 0; m < 2; m++)
      af[m] = *(const half8*)&As[cur][(wr * 32 + m * 16 + fr) * 32 + rswz];
#pragma unroll
    for (int n = 0; n < 4; n++)
      bf[n] = *(const half8*)&Bs[cur][(wc * 64 + n * 16 + fr) * 32 + rswz];
    __builtin_amdgcn_s_setprio(1);
#pragma unroll
    for (int m = 0; m < 2; m++)
#pragma unroll
      for (int n = 0; n < 4; n++)
        acc[m][n] = MFMA16(af[m], bf[n], acc[m][n]);
    __builtin_amdgcn_s_setprio(0);

    __syncthreads();   // drains prefetch vmcnt + protects buffer reuse
  }
#undef GSTAGE

  const int rl = (l >> 4) * 4;
  const int cl = l & 15;
#pragma unroll
  for (int m = 0; m < 2; m++) {
#pragma unroll
    for (int n = 0; n < 4; n++) {
#pragma unroll
      for (int j = 0; j < 4; j++) {
        int grow = row0 + wr * 32 + m * 16 + rl + j;
        int gcol = col0 + wc * 64 + n * 16 + cl;
        float v = acc[m][n][j];
        if (MODE == 0) {
          int b = grow >> 11, s = grow & 2047;
          if (gcol < 2048) {
            float v2 = (v + bias1[gcol]) * 0.1803368801111137f; // (1/8)*log2(e)
            int h = gcol >> 6, d = gcol & 63;
            outQ[((size_t)((b * NHQ + h) * S_LEN + s)) * 64 + d] = (_Float16)v2;
          } else if (gcol < 2560) {
            int kc = gcol - 2048;
            float v2 = v + bias2[kc];
            int h = kc >> 6, d = kc & 63;
            outK[((size_t)((b * NHKV + h) * S_LEN + s)) * 64 + d] = (_Float16)v2;
          } else {
            int vc = gcol - 2560;
            float v2 = v + bias3[vc];
            int h = vc >> 6, d = vc & 63;
            int sl = s & 63;
            int pos = (sl & 51) | ((sl & 4) << 1) | ((sl & 8) >> 1); // sigma: swap b2,b3
            int col = (s & ~63) | (pos ^ ((d & 7) * 8));             // + bank swizzle
            outV[((size_t)((b * NHKV + h) * 64 + d)) * 2048 + col] = (_Float16)v2;
          }
        } else {
          float v2 = v + bias1[gcol];
          outF[(size_t)grow * DMODEL + gcol] = v2;
        }
      }
    }
  }
}

// ---------------- flash attention (32x32x16 MFMA, P in registers) ----------------
// Qs: [b,h,s][64] fp16 (Q*log2e/8), Ks: [b,hk,s][64],
// Vt: [b,hk,d][2048] fp16 (sigma key perm + d-octet bank swizzle baked in)
// Ao: [t][2048] fp16.  QBLK=256, 8 waves x 32q.
// r16: KVBLK=128 — two 64-key sub-tiles per barrier (barriers 32->16, 2x
// compiler scheduling window; QKb independent of SMa/PVa). Same math order
// as sequential 64-key tiles -> bit-identical output. No online max.
__global__ __launch_bounds__(512, 4) void fa_kernel(
    const _Float16* __restrict__ Qs, const _Float16* __restrict__ Ks,
    const _Float16* __restrict__ Vt, _Float16* __restrict__ Ao)
{
  // [0..3] K: buf0{a,b}, buf1{a,b}; [4..7] V same. 8 KB per subtile, 64 KB total.
  __shared__ __align__(16) _Float16 SM[8][64 * 64];
  const int tid = threadIdx.x;
  const int w = tid >> 6, l = tid & 63;   // w in 0..7
  const int q0 = blockIdx.x * 256;
  const int bh = blockIdx.y;
  const int b = bh >> 5, hh = bh & 31, hk = hh >> 2;

  const _Float16* Qg = Qs + ((size_t)(b * NHQ + hh) * S_LEN) * 64;
  const _Float16* Kg = Ks + ((size_t)(b * NHKV + hk) * S_LEN) * 64;
  const _Float16* Vg = Vt + ((size_t)(b * NHKV + hk) * 64) * 2048;

  const int lq = l & 31;   // q column (B col) / d row (A row)
  const int hf = l >> 5;   // k-slot half selector
  const int lx7 = lq & 7;

  // Q fragments: B[k=d][col=q]; lane holds Q[q0+w*32+lq][dc*16 + hf*8 + e]
  half8 qf[4];
  {
    const _Float16* qrow = Qg + (size_t)(q0 + w * 32 + lq) * 64 + hf * 8;
#pragma unroll
    for (int dc = 0; dc < 4; dc++)
      qf[dc] = *(const half8*)&qrow[dc * 16];
  }

  // tile-invariant per-lane LDS byte offsets (row 32+lq via +4096 imm;
  // subtile b via +8192; V via +32768; alt buffer via +16384 base add)
  const char* smb = (const char*)&SM[0][0];
  int aoff[4];
#pragma unroll
  for (int dc = 0; dc < 4; dc++)
    aoff[dc] = lq * 128 + (((dc * 2 + hf) ^ lx7) * 16);

  // staging: each wave stages 8 rows of K and 8 rows (d) of V per sub-tile
  const int sr0 = w * 8 + (l >> 3);
  const _Float16* kp = Kg + (size_t)sr0 * 64 + 8 * ((l & 7) ^ (sr0 & 7));
  const _Float16* vp = Vg + (size_t)sr0 * 2048 + 8 * (l & 7);   // LINEAR source

  f32x16 acc0 = {}, acc1 = {};
  float lsum = 0.f;

  // stage key-tiles 2tp, 2tp+1 into buffer pair `buf`
#define STAGE(buf, tp)                                                        \
  {                                                                           \
    gload16(kp + (size_t)(2 * (tp)) * 4096,     &SM[2 * (buf)][(w * 8) * 64]);     \
    gload16(kp + (size_t)(2 * (tp) + 1) * 4096, &SM[2 * (buf) + 1][(w * 8) * 64]); \
    gload16(vp + (size_t)(2 * (tp)) * 64,       &SM[4 + 2 * (buf)][(w * 8) * 64]); \
    gload16(vp + (size_t)(2 * (tp) + 1) * 64,   &SM[4 + 2 * (buf) + 1][(w * 8) * 64]); \
  }

  // one 64-key sub-tile: QK -> exp/pack/lsum -> PV  (kb = K subtile base)
#define SUBTILE(kb)                                                           \
  {                                                                           \
    f32x16 s0 = {}, s1 = {};                                                  \
    __builtin_amdgcn_s_setprio(1);                                            \
    _Pragma("unroll")                                                         \
    for (int dc = 0; dc < 4; dc++) {                                          \
      const char* p = (kb) + aoff[dc];                                        \
      half8 kf0 = *(const half8*)p;                                           \
      half8 kf1 = *(const half8*)(p + 4096);                                  \
      s0 = MFMA32(kf0, qf[dc], s0);                                           \
      s1 = MFMA32(kf1, qf[dc], s1);                                           \
    }                                                                         \
    __builtin_amdgcn_s_setprio(0);                                            \
    half8 pf[4];                                                              \
    PACKC(0, s0) PACKC(1, s0) PACKC(2, s1) PACKC(3, s1)                       \
    const char* vb = (kb) + 32768;                                            \
    __builtin_amdgcn_s_setprio(1);                                            \
    _Pragma("unroll")                                                         \
    for (int c = 0; c < 4; c++) {                                             \
      const char* p = vb + aoff[c];                                           \
      half8 vf0 = *(const half8*)p;                                           \
      half8 vf1 = *(const half8*)(p + 4096);                                  \
      acc0 = MFMA32(vf0, pf[c], acc0);                                        \
      acc1 = MFMA32(vf1, pf[c], acc1);                                        \
    }                                                                         \
    __builtin_amdgcn_s_setprio(0);                                            \
  }

#define PACKC(c, SA)                                                          \
    {                                                                         \
      float e0 = fexp2(SA[8 * ((c) & 1) + 0]), e1 = fexp2(SA[8 * ((c) & 1) + 1]); \
      float e2 = fexp2(SA[8 * ((c) & 1) + 2]), e3 = fexp2(SA[8 * ((c) & 1) + 3]); \
      float e4 = fexp2(SA[8 * ((c) & 1) + 4]), e5 = fexp2(SA[8 * ((c) & 1) + 5]); \
      float e6 = fexp2(SA[8 * ((c) & 1) + 6]), e7 = fexp2(SA[8 * ((c) & 1) + 7]); \
      lsum += ((e0 + e1) + (e2 + e3)) + ((e4 + e5) + (e6 + e7));              \
      int4 pi;                                                                \
      pi.x = cvt_pk(e0, e1); pi.y = cvt_pk(e2, e3);                           \
      pi.z = cvt_pk(e4, e5); pi.w = cvt_pk(e6, e7);                           \
      pf[c] = __builtin_bit_cast(half8, pi);                                  \
    }

  STAGE(0, 0);
  __syncthreads();

  const int NTP = S_LEN / 128;   // tile pairs
  int cur = 0;
  for (int tp = 0; tp < NTP; tp++) {
    if (tp + 1 < NTP) STAGE(cur ^ 1, tp + 1);
    const char* kbase = smb + cur * 16384;
    SUBTILE(kbase)            // keys 128*tp ..      (subtile a)
    SUBTILE(kbase + 8192)     // keys 128*tp + 64 .. (subtile b)
    __syncthreads();          // drains prefetch vmcnt + releases buffers
    cur ^= 1;
  }
#undef PACKC
#undef SUBTILE
#undef STAGE

  // lane holds half the keys of q-column lq; other half is in lane^32
  float tot = lsum + __shfl_xor(lsum, 32);
  const float inv = 1.0f / tot;
  _Float16* abase = Ao + ((size_t)(b * S_LEN + q0 + w * 32 + lq)) * DMODEL + hh * 64;
#pragma unroll
  for (int dt = 0; dt < 2; dt++) {
#pragma unroll
    for (int mreg = 0; mreg < 4; mreg++) {
      half4v hv;
#pragma unroll
      for (int j = 0; j < 4; j++) {
        float v = (dt == 0 ? acc0[mreg * 4 + j] : acc1[mreg * 4 + j]) * inv;
        hv[j] = (_Float16)v;
      }
      *(half4v*)&abase[dt * 32 + mreg * 8 + hf * 4] = hv;
    }
  }
}

// ---------------- launch ----------------
extern "C" void kernel_launch(void* const* d_in, const int* in_sizes, int n_in,
                              void* d_out, int out_size, void* d_ws, size_t ws_size,
                              hipStream_t stream) {
  const float* x   = (const float*)d_in[0];
  const float* W_q = (const float*)d_in[1];
  const float* b_q = (const float*)d_in[2];
  const float* W_k = (const float*)d_in[3];
  const float* b_k = (const float*)d_in[4];
  const float* W_v = (const float*)d_in[5];
  const float* b_v = (const float*)d_in[6];
  const float* W_o = (const float*)d_in[7];
  const float* b_o = (const float*)d_in[8];

  char* ws = (char*)d_ws;
  _Float16* xs    = (_Float16*)(ws);                         // 16 MB
  _Float16* Wall  = (_Float16*)(ws + (16ull << 20));         // 12 MB [3072][2048]
  _Float16* Wo_t  = (_Float16*)(ws + (28ull << 20));         //  8 MB
  _Float16* Qsb   = (_Float16*)(ws + (36ull << 20));         // 16 MB
  _Float16* Ksb   = (_Float16*)(ws + (68ull << 20));         //  4 MB
  _Float16* Vtb   = (_Float16*)(ws + (80ull << 20));         //  4 MB
  _Float16* Ao    = (_Float16*)(ws + (88ull << 20));         // 16 MB

  prep_all<<<dim3(64, 288), 256, 0, stream>>>(x, W_q, W_k, W_v, W_o, xs, Wall, Wo_t);

  gemm_nt<0><<<dim3(32, 24), 512, 0, stream>>>(xs, Wall, 2048, b_q, b_k, b_v,
                                               Qsb, Ksb, Vtb, nullptr);
  fa_kernel<<<dim3(8, 64), 512, 0, stream>>>(Qsb, Ksb, Vtb, Ao);
  gemm_nt<2><<<dim3(32, 16), 512, 0, stream>>>(Ao, Wo_t, 2048, b_o, nullptr, nullptr,
                                               nullptr, nullptr, nullptr, (float*)d_out);
}

// Round 17
// 224.706 us; speedup vs baseline: 1.0224x; 1.0224x over previous
//
#include <hip/hip_runtime.h>
#include <stdint.h>

#define S_LEN 2048
#define NTOK  4096      // B*S
#define DMODEL 2048
#define NHQ 32
#define NHKV 8

typedef _Float16 half8 __attribute__((ext_vector_type(8)));
typedef _Float16 half4v __attribute__((ext_vector_type(4)));
typedef __fp16 fp16x2 __attribute__((ext_vector_type(2)));
typedef float f32x4 __attribute__((ext_vector_type(4)));
typedef float f32x16 __attribute__((ext_vector_type(16)));

#define MFMA16(a,b,c) __builtin_amdgcn_mfma_f32_16x16x32_f16(a,b,c,0,0,0)
#define MFMA32(a,b,c) __builtin_amdgcn_mfma_f32_32x32x16_f16(a,b,c,0,0,0)

__device__ __forceinline__ void gload16(const void* g, void* l) {
  __builtin_amdgcn_global_load_lds(
      (const __attribute__((address_space(1))) void*)g,
      (__attribute__((address_space(3))) void*)l, 16, 0, 0);
}

__device__ __forceinline__ float fexp2(float x) {
#if __has_builtin(__builtin_amdgcn_exp2f)
  return __builtin_amdgcn_exp2f(x);
#else
  float r; asm("v_exp_f32 %0, %1" : "=v"(r) : "v"(x)); return r;
#endif
}

__device__ __forceinline__ int cvt_pk(float a, float b) {
  fp16x2 r = __builtin_amdgcn_cvt_pkrtz(a, b);
  return __builtin_bit_cast(int, r);
}

// ---------------- prep kernel (weight transposes + x cast, one launch) ----------------
// blockIdx.y: 0-63 Wq | 64-79 Wk | 80-95 Wv | 96-159 Wo | 160-287 cast_x
__global__ void prep_all(const float* __restrict__ x,
                         const float* __restrict__ Wq, const float* __restrict__ Wk,
                         const float* __restrict__ Wv, const float* __restrict__ Wo,
                         _Float16* __restrict__ xs,
                         _Float16* __restrict__ Wall, _Float16* __restrict__ Wot) {
  __shared__ float tile[32][33];
  const int K = 2048;
  int y = blockIdx.y;
  if (y >= 160) {   // cast_x: fp32 [NTOK][DMODEL] -> fp16
    size_t bi = (size_t)(y - 160) * 64 + blockIdx.x;
    size_t i = (bi * 256 + threadIdx.x) * 4;
    float4 v = *(const float4*)(x + i);
    half4v o = {(_Float16)v.x, (_Float16)v.y, (_Float16)v.z, (_Float16)v.w};
    *(half4v*)(xs + i) = o;
    return;
  }
  const float* W;
  _Float16* Wt;
  int N;
  if (y < 64)      { W = Wq; Wt = Wall;                          N = 2048; }
  else if (y < 80) { W = Wk; Wt = Wall + (size_t)2048 * 2048;    N = 512;  y -= 64; }
  else if (y < 96) { W = Wv; Wt = Wall + (size_t)2560 * 2048;    N = 512;  y -= 80; }
  else             { W = Wo; Wt = Wot;                           N = 2048; y -= 96; }
  int kt = blockIdx.x * 32, nt = y * 32;
  int r = threadIdx.x >> 5, c = threadIdx.x & 31;
#pragma unroll
  for (int i = 0; i < 4; i++)
    tile[r + i * 8][c] = W[(size_t)(kt + r + i * 8) * N + nt + c];
  __syncthreads();
#pragma unroll
  for (int i = 0; i < 4; i++) {
    int rr = r + i * 8;
    Wt[(size_t)(nt + rr) * K + kt + c] = (_Float16)tile[c][rr];
  }
}

// ---------------- GEMM: C = A(MxK) * Bt(NxK)^T, fp16 in / fp32 acc ----------------
// 128x128 tile, BK=32, 512 threads (8 waves, 4Mx2N, wave tile 32x64),
// double-buffered prefetch (T3-min) + XCD swizzle (T1). (r13 known-good.)
// MODE 0: fused QKV epilogue (N=3072); MODE 2: O epilogue (N=2048).
template<int MODE>
__global__ __launch_bounds__(512, 6) void gemm_nt(
    const _Float16* __restrict__ A, const _Float16* __restrict__ Bt, int K,
    const float* __restrict__ bias1, const float* __restrict__ bias2,
    const float* __restrict__ bias3,
    _Float16* __restrict__ outQ, _Float16* __restrict__ outK,
    _Float16* __restrict__ outV, float* __restrict__ outF)
{
  __shared__ __align__(16) _Float16 As[2][128 * 32];
  __shared__ __align__(16) _Float16 Bs[2][128 * 32];
  const int tid = threadIdx.x;
  const int w = tid >> 6, l = tid & 63;
  const int wr = w >> 1, wc = w & 1;   // 4 M-quadrants x 2 N-halves

  // T1: bijective XCD swizzle (nwg multiple of 8; gridDim.x == 32)
  const int lin = blockIdx.x + blockIdx.y * 32;
  const int nwg = 32 * gridDim.y;
  const int swz = (lin & 7) * (nwg >> 3) + (lin >> 3);
  const int row0 = (swz & 31) * 128, col0 = (swz >> 5) * 128;

  f32x4 acc[2][4] = {};

  const int lr = l >> 2;                      // staging row-in-16
  const int scol = 8 * ((l & 3) ^ (lr & 3));  // pre-swizzled source col
  const _Float16* Abase = A + (size_t)row0 * K;
  const _Float16* Bbase = Bt + (size_t)col0 * K;

  const int fr = l & 15;
  const int rswz = 8 * ((l >> 4) ^ (l & 3));  // kk ^ ((row&3)*8)

  // wave w stages rows w*16..w*16+15 of both tiles: 1 A + 1 B gload per thread
#define GSTAGE(buf, kt)                                                       \
  {                                                                           \
    int r = w * 16 + lr;                                                      \
    gload16(Abase + (size_t)r * K + (kt) * 32 + scol, &As[buf][(w * 16) * 32]); \
    gload16(Bbase + (size_t)r * K + (kt) * 32 + scol, &Bs[buf][(w * 16) * 32]); \
  }

  const int NK = K >> 5;
  GSTAGE(0, 0);
  __syncthreads();

  for (int kt = 0; kt < NK; kt++) {
    const int cur = kt & 1;
    if (kt + 1 < NK) GSTAGE(cur ^ 1, kt + 1);

    half8 af[2], bf[4];
#pragma unroll
    for (int m = 0; m < 2; m++)
      af[m] = *(const half8*)&As[cur][(wr * 32 + m * 16 + fr) * 32 + rswz];
#pragma unroll
    for (int n = 0; n < 4; n++)
      bf[n] = *(const half8*)&Bs[cur][(wc * 64 + n * 16 + fr) * 32 + rswz];
    __builtin_amdgcn_s_setprio(1);
#pragma unroll
    for (int m = 0; m < 2; m++)
#pragma unroll
      for (int n = 0; n < 4; n++)
        acc[m][n] = MFMA16(af[m], bf[n], acc[m][n]);
    __builtin_amdgcn_s_setprio(0);

    __syncthreads();   // drains prefetch vmcnt + protects buffer reuse
  }
#undef GSTAGE

  const int rl = (l >> 4) * 4;
  const int cl = l & 15;
#pragma unroll
  for (int m = 0; m < 2; m++) {
#pragma unroll
    for (int n = 0; n < 4; n++) {
#pragma unroll
      for (int j = 0; j < 4; j++) {
        int grow = row0 + wr * 32 + m * 16 + rl + j;
        int gcol = col0 + wc * 64 + n * 16 + cl;
        float v = acc[m][n][j];
        if (MODE == 0) {
          int b = grow >> 11, s = grow & 2047;
          if (gcol < 2048) {
            float v2 = (v + bias1[gcol]) * 0.1803368801111137f; // (1/8)*log2(e)
            int h = gcol >> 6, d = gcol & 63;
            outQ[((size_t)((b * NHQ + h) * S_LEN + s)) * 64 + d] = (_Float16)v2;
          } else if (gcol < 2560) {
            int kc = gcol - 2048;
            float v2 = v + bias2[kc];
            int h = kc >> 6, d = kc & 63;
            outK[((size_t)((b * NHKV + h) * S_LEN + s)) * 64 + d] = (_Float16)v2;
          } else {
            int vc = gcol - 2560;
            float v2 = v + bias3[vc];
            int h = vc >> 6, d = vc & 63;
            int sl = s & 63;
            int pos = (sl & 51) | ((sl & 4) << 1) | ((sl & 8) >> 1); // sigma: swap b2,b3
            int col = (s & ~63) | (pos ^ ((d & 7) * 8));             // + bank swizzle
            outV[((size_t)((b * NHKV + h) * 64 + d)) * 2048 + col] = (_Float16)v2;
          }
        } else {
          float v2 = v + bias1[gcol];
          outF[(size_t)grow * DMODEL + gcol] = v2;
        }
      }
    }
  }
}

// ---------------- flash attention (32x32x16 MFMA, P in registers) ----------------
// Qs: [b,h,s][64] fp16 (Q*log2e/8), Ks: [b,hk,s][64],
// Vt: [b,hk,d][2048] fp16 (sigma key perm + d-octet bank swizzle baked in)
// Ao: [t][2048] fp16.  QBLK=256, 8 waves x 32q (r15 known-good structure;
// r16 KVBLK=128 regressed — reverted). No online max; 1/sum cancels.
// r17: XCD-chunked block mapping — each XCD owns 64 consecutive work items
// (= 8 bh values, 2 KV-groups, 1 MB K/V) so the 32-fold K/V reuse is
// L2-resident instead of streamed from L3.
__global__ __launch_bounds__(512, 4) void fa_kernel(
    const _Float16* __restrict__ Qs, const _Float16* __restrict__ Ks,
    const _Float16* __restrict__ Vt, _Float16* __restrict__ Ao)
{
  // [0]=K buf0, [1]=K buf1, [2]=V buf0, [3]=V buf1  (8192 B each)
  __shared__ __align__(16) _Float16 SM[4][64 * 64];
  const int tid = threadIdx.x;
  const int w = tid >> 6, l = tid & 63;   // w in 0..7
  // XCD-chunked bijective remap (512 blocks = 8 XCDs x 64)
  const int lin = blockIdx.x + blockIdx.y * 8;
  const int swz = (lin & 7) * 64 + (lin >> 3);
  const int q0 = (swz & 7) * 256;
  const int bh = swz >> 3;
  const int b = bh >> 5, hh = bh & 31, hk = hh >> 2;

  const _Float16* Qg = Qs + ((size_t)(b * NHQ + hh) * S_LEN) * 64;
  const _Float16* Kg = Ks + ((size_t)(b * NHKV + hk) * S_LEN) * 64;
  const _Float16* Vg = Vt + ((size_t)(b * NHKV + hk) * 64) * 2048;

  const int lq = l & 31;   // q column (B col) / d row (A row)
  const int hf = l >> 5;   // k-slot half selector
  const int lx7 = lq & 7;

  // Q fragments: B[k=d][col=q]; lane holds Q[q0+w*32+lq][dc*16 + hf*8 + e]
  half8 qf[4];
  {
    const _Float16* qrow = Qg + (size_t)(q0 + w * 32 + lq) * 64 + hf * 8;
#pragma unroll
    for (int dc = 0; dc < 4; dc++)
      qf[dc] = *(const half8*)&qrow[dc * 16];
  }

  // tile-invariant per-lane LDS byte offsets (rows lq / 32+lq via +4096 imm;
  // V via +16384 imm; alt buffer via +8192 base add)
  const char* smb = (const char*)&SM[0][0];
  int aoff[4];
#pragma unroll
  for (int dc = 0; dc < 4; dc++)
    aoff[dc] = lq * 128 + (((dc * 2 + hf) ^ lx7) * 16);

  // staging: each wave stages 8 rows of K and 8 rows (d) of V per tile
  const int sr0 = w * 8 + (l >> 3);
  const _Float16* kp = Kg + (size_t)sr0 * 64 + 8 * ((l & 7) ^ (sr0 & 7));
  const _Float16* vp = Vg + (size_t)sr0 * 2048 + 8 * (l & 7);   // LINEAR source

  f32x16 acc0 = {}, acc1 = {};
  float lsum = 0.f;

#define STAGE(buf, t)                                                         \
  {                                                                           \
    gload16(kp + (size_t)(t) * 4096, &SM[buf][(w * 8) * 64]);                 \
    gload16(vp + (size_t)(t) * 64, &SM[2 + (buf)][(w * 8) * 64]);             \
  }

  STAGE(0, 0);
  __syncthreads();

  const int NT = S_LEN / 64;
  int cur = 0;
  for (int t = 0; t < NT; t++) {
    if (t + 1 < NT) STAGE(cur ^ 1, t + 1);

    const char* kb = smb + cur * 8192;

    // swapped QK^T: s0/s1 = S^T for key-halves 0/1; lane holds q-column lq
    f32x16 s0 = {}, s1 = {};
    __builtin_amdgcn_s_setprio(1);
#pragma unroll
    for (int dc = 0; dc < 4; dc++) {
      const char* p = kb + aoff[dc];
      half8 kf0 = *(const half8*)p;
      half8 kf1 = *(const half8*)(p + 4096);
      s0 = MFMA32(kf0, qf[dc], s0);
      s1 = MFMA32(kf1, qf[dc], s1);
    }
    __builtin_amdgcn_s_setprio(0);

    // p = exp2(score); C/D regs [8c..8c+7] ARE the PV B-frag for slot-chunk c
    // (sigma key perm baked into V). Denominator: fp32 chunk sums -> lsum.
    half8 pf[4];
#define PACKC(c, SA)                                                          \
    {                                                                         \
      float e0 = fexp2(SA[8 * ((c) & 1) + 0]), e1 = fexp2(SA[8 * ((c) & 1) + 1]); \
      float e2 = fexp2(SA[8 * ((c) & 1) + 2]), e3 = fexp2(SA[8 * ((c) & 1) + 3]); \
      float e4 = fexp2(SA[8 * ((c) & 1) + 4]), e5 = fexp2(SA[8 * ((c) & 1) + 5]); \
      float e6 = fexp2(SA[8 * ((c) & 1) + 6]), e7 = fexp2(SA[8 * ((c) & 1) + 7]); \
      lsum += ((e0 + e1) + (e2 + e3)) + ((e4 + e5) + (e6 + e7));              \
      int4 pi;                                                                \
      pi.x = cvt_pk(e0, e1); pi.y = cvt_pk(e2, e3);                           \
      pi.z = cvt_pk(e4, e5); pi.w = cvt_pk(e6, e7);                           \
      pf[c] = __builtin_bit_cast(half8, pi);                                  \
    }
    PACKC(0, s0) PACKC(1, s0) PACKC(2, s1) PACKC(3, s1)
#undef PACKC

    // PV: O^T[d][q] += mfma(A=V^T, B=P^T)
    const char* vb = kb + 16384;
    __builtin_amdgcn_s_setprio(1);
#pragma unroll
    for (int c = 0; c < 4; c++) {
      const char* p = vb + aoff[c];
      half8 vf0 = *(const half8*)p;
      half8 vf1 = *(const half8*)(p + 4096);
      acc0 = MFMA32(vf0, pf[c], acc0);
      acc1 = MFMA32(vf1, pf[c], acc1);
    }
    __builtin_amdgcn_s_setprio(0);

    __syncthreads();   // drains prefetch vmcnt + releases buffers
    cur ^= 1;
  }

  // lane holds half the keys of q-column lq; other half is in lane^32
  float tot = lsum + __shfl_xor(lsum, 32);
  const float inv = 1.0f / tot;
  _Float16* abase = Ao + ((size_t)(b * S_LEN + q0 + w * 32 + lq)) * DMODEL + hh * 64;
#pragma unroll
  for (int dt = 0; dt < 2; dt++) {
#pragma unroll
    for (int mreg = 0; mreg < 4; mreg++) {
      half4v hv;
#pragma unroll
      for (int j = 0; j < 4; j++) {
        float v = (dt == 0 ? acc0[mreg * 4 + j] : acc1[mreg * 4 + j]) * inv;
        hv[j] = (_Float16)v;
      }
      *(half4v*)&abase[dt * 32 + mreg * 8 + hf * 4] = hv;
    }
  }
#undef STAGE
}

// ---------------- launch ----------------
extern "C" void kernel_launch(void* const* d_in, const int* in_sizes, int n_in,
                              void* d_out, int out_size, void* d_ws, size_t ws_size,
                              hipStream_t stream) {
  const float* x   = (const float*)d_in[0];
  const float* W_q = (const float*)d_in[1];
  const float* b_q = (const float*)d_in[2];
  const float* W_k = (const float*)d_in[3];
  const float* b_k = (const float*)d_in[4];
  const float* W_v = (const float*)d_in[5];
  const float* b_v = (const float*)d_in[6];
  const float* W_o = (const float*)d_in[7];
  const float* b_o = (const float*)d_in[8];

  char* ws = (char*)d_ws;
  _Float16* xs    = (_Float16*)(ws);                         // 16 MB
  _Float16* Wall  = (_Float16*)(ws + (16ull << 20));         // 12 MB [3072][2048]
  _Float16* Wo_t  = (_Float16*)(ws + (28ull << 20));         //  8 MB
  _Float16* Qsb   = (_Float16*)(ws + (36ull << 20));         // 16 MB
  _Float16* Ksb   = (_Float16*)(ws + (68ull << 20));         //  4 MB
  _Float16* Vtb   = (_Float16*)(ws + (80ull << 20));         //  4 MB
  _Float16* Ao    = (_Float16*)(ws + (88ull << 20));         // 16 MB

  prep_all<<<dim3(64, 288), 256, 0, stream>>>(x, W_q, W_k, W_v, W_o, xs, Wall, Wo_t);

  gemm_nt<0><<<dim3(32, 24), 512, 0, stream>>>(xs, Wall, 2048, b_q, b_k, b_v,
                                               Qsb, Ksb, Vtb, nullptr);
  fa_kernel<<<dim3(8, 64), 512, 0, stream>>>(Qsb, Ksb, Vtb, Ao);
  gemm_nt<2><<<dim3(32, 16), 512, 0, stream>>>(Ao, Wo_t, 2048, b_o, nullptr, nullptr,
                                               nullptr, nullptr, nullptr, (float*)d_out);
}